// Round 11
// baseline (146.125 us; speedup 1.0000x reference)
//
#include <hip/hip_runtime.h>
#include <hip/hip_fp16.h>

#define N_NODES 50000
#define N_EDGES 800000
#define D_FEAT  64
#define CAP     32                      // csr slots/node; P(deg>32|Poisson16)~1e-5
#define SPILL_CAP 262144                // 2 MB; ~0 used in practice
#define PART_MAGIC 687195ull            // ceil(2^32/6250); dst/6250 for dst<2^16

#define STAGE_BLOCKS 1024
#define QPB 196                         // quads per stage block (1024*196 >= 200000)
#define BIN_CAP 192                     // per-partition LDS bin (mean 98, >10 sigma)
#define BUILD_BLOCKS 2048               // 8 partitions x 256 blocks

// ---------------------------------------------------------------------------
// Round 11: read-once staged fill (kills the 8x redundant partition reads).
//   1. memset cnt+spillcnt (0.2 MB)
//   2. stage: each block reads its contiguous edge chunk ONCE, bins edges
//      into 8 per-partition LDS buckets (LDS atomics, no cross-block
//      contention), flushes to fixed per-(block,part) staging slots with
//      coalesced 8B stores. Also fp32->fp16 queue convert (grid-stride).
//   3. build: block b -> partition p=b&7 (round-robin XCD); one wave per
//      staged segment; cnt-atomic + 4B csr store, all within the owning
//      XCD's L2 (csr/cnt per partition fit in 4MB L2).
//   4. pull: unchanged R10 (one wave/node, 16 fp16 128B gathers in flight,
//      masked tail, wave-uniform spill scan, 256B store).
// Entry format everywhere: u.x = (dst<<16)|src, u.y = fp32 weight bits.
// ---------------------------------------------------------------------------

__device__ __forceinline__ unsigned pack_entry(unsigned s, float w) {
    return (s << 16) | (unsigned)__half_as_ushort(__float2half(w));
}
__device__ __forceinline__ float entry_w(unsigned e) {
    return __half2float(__ushort_as_half((unsigned short)(e & 0xffffu)));
}
__device__ __forceinline__ int part_of(int d) {
    return (int)(((unsigned long long)(unsigned)d * PART_MAGIC) >> 32);
}

__global__ void __launch_bounds__(256)
stage_kernel(const int* __restrict__ src, const int* __restrict__ dst,
             const float* __restrict__ weight, const float* __restrict__ queue,
             __half* __restrict__ qh, uint2* __restrict__ stagebuf,
             int* __restrict__ bincnt, uint2* __restrict__ spill,
             int* __restrict__ spillcnt) {
    __shared__ uint2 bins[8][BIN_CAP];          // 12 KB
    __shared__ int bcnt[8];
    const int tid = threadIdx.x;
    const int blk = blockIdx.x;
    if (tid < 8) bcnt[tid] = 0;
    __syncthreads();

    const int q0 = blk * QPB;
    const int q1 = min(q0 + QPB, N_EDGES / 4);
    for (int t = q0 + tid; t < q1; t += 256) {  // <=1 iteration per thread
        const int4   s4 = reinterpret_cast<const int4*>(src)[t];
        const int4   d4 = reinterpret_cast<const int4*>(dst)[t];
        const float4 w4 = reinterpret_cast<const float4*>(weight)[t];
        const int   ss[4] = {s4.x, s4.y, s4.z, s4.w};
        const int   dd[4] = {d4.x, d4.y, d4.z, d4.w};
        const float ww[4] = {w4.x, w4.y, w4.z, w4.w};
#pragma unroll
        for (int j = 0; j < 4; ++j) {
            const int p = part_of(dd[j]);
            const uint2 e = make_uint2(((unsigned)dd[j] << 16) | (unsigned)ss[j],
                                       __float_as_uint(ww[j]));
            int pos = atomicAdd(&bcnt[p], 1);   // LDS atomic
            if (pos < BIN_CAP) {
                bins[p][pos] = e;
            } else {                            // ~never (>10 sigma)
                int sp = atomicAdd(spillcnt, 1);
                if (sp < SPILL_CAP) spill[sp] = e;
            }
        }
    }
    __syncthreads();

    // Flush: wave w handles bins w and w+4; coalesced 8B stores.
    const int wv = tid >> 6, lane = tid & 63;
#pragma unroll
    for (int k = 0; k < 2; ++k) {
        const int p = wv + k * 4;
        const int c = min(bcnt[p], BIN_CAP);
        uint2* dstp = stagebuf + ((size_t)p * STAGE_BLOCKS + blk) * BIN_CAP;
        for (int i = lane; i < c; i += 64) dstp[i] = bins[p][i];
        if (lane == 0) bincnt[blk * 8 + p] = c;
    }

    // Fused queue fp32 -> fp16 convert (coalesced float4 read, 8B write).
    const int gtid = blk * 256 + tid;           // 262144 threads
    for (int t = gtid; t < N_NODES * D_FEAT / 4; t += STAGE_BLOCKS * 256) {
        const float4 q = reinterpret_cast<const float4*>(queue)[t];
        ushort4 h;
        h.x = __half_as_ushort(__float2half(q.x));
        h.y = __half_as_ushort(__float2half(q.y));
        h.z = __half_as_ushort(__float2half(q.z));
        h.w = __half_as_ushort(__float2half(q.w));
        reinterpret_cast<ushort4*>(qh)[t] = h;
    }
}

__global__ void __launch_bounds__(256)
build_kernel(const uint2* __restrict__ stagebuf, const int* __restrict__ bincnt,
             int* __restrict__ cnt, unsigned* __restrict__ csr,
             uint2* __restrict__ spill, int* __restrict__ spillcnt) {
    const int p   = blockIdx.x & 7;             // XCD id (round-robin dispatch)
    const int bip = blockIdx.x >> 3;            // 0..255 within partition
    const int wv  = threadIdx.x >> 6, lane = threadIdx.x & 63;

    const int s = bip * 4 + wv;                 // one segment per wave (1024 total)
    if (s >= STAGE_BLOCKS) return;
    const int c = bincnt[s * 8 + p];
    const uint2* seg = stagebuf + ((size_t)p * STAGE_BLOCKS + s) * BIN_CAP;

    for (int i = lane; i < c; i += 64) {
        const uint2 u = seg[i];
        const int d = (int)(u.x >> 16);
        const float w = __uint_as_float(u.y);
        int pos = atomicAdd(&cnt[d], 1);        // L2-local to this XCD
        if (pos < CAP) {
            csr[(size_t)d * CAP + pos] = pack_entry(u.x & 0xffffu, w);
        } else {
            int sp = atomicAdd(spillcnt, 1);
            if (sp < SPILL_CAP) spill[sp] = u;
        }
    }
}

// One wave per node; 4 nodes per 256-thread block. 16 gathers in flight.
__global__ void __launch_bounds__(256)
pull_kernel(const __half* __restrict__ qh, const float* __restrict__ queue,
            const unsigned* __restrict__ csr, const int* __restrict__ cnt,
            const uint2* __restrict__ spill, const int* __restrict__ spillcnt,
            float* __restrict__ out) {
    const int node = blockIdx.x * 4 + (threadIdx.x >> 6);
    const int lane = threadIdx.x & 63;
    if (node >= N_NODES) return;

    const unsigned* p = csr + (size_t)node * CAP;
    const int c = min(cnt[node], CAP);

    float acc = 0.0f;
    int i = 0;
    for (; i + 16 <= c; i += 16) {              // 16 independent 128B gathers
        uint4 ea = *reinterpret_cast<const uint4*>(p + i);
        uint4 eb = *reinterpret_cast<const uint4*>(p + i + 4);
        uint4 ec = *reinterpret_cast<const uint4*>(p + i + 8);
        uint4 ed = *reinterpret_cast<const uint4*>(p + i + 12);
        float q0  = __half2float(qh[(size_t)(ea.x >> 16) * D_FEAT + lane]);
        float q1  = __half2float(qh[(size_t)(ea.y >> 16) * D_FEAT + lane]);
        float q2  = __half2float(qh[(size_t)(ea.z >> 16) * D_FEAT + lane]);
        float q3  = __half2float(qh[(size_t)(ea.w >> 16) * D_FEAT + lane]);
        float q4  = __half2float(qh[(size_t)(eb.x >> 16) * D_FEAT + lane]);
        float q5  = __half2float(qh[(size_t)(eb.y >> 16) * D_FEAT + lane]);
        float q6  = __half2float(qh[(size_t)(eb.z >> 16) * D_FEAT + lane]);
        float q7  = __half2float(qh[(size_t)(eb.w >> 16) * D_FEAT + lane]);
        float q8  = __half2float(qh[(size_t)(ec.x >> 16) * D_FEAT + lane]);
        float q9  = __half2float(qh[(size_t)(ec.y >> 16) * D_FEAT + lane]);
        float q10 = __half2float(qh[(size_t)(ec.z >> 16) * D_FEAT + lane]);
        float q11 = __half2float(qh[(size_t)(ec.w >> 16) * D_FEAT + lane]);
        float q12 = __half2float(qh[(size_t)(ed.x >> 16) * D_FEAT + lane]);
        float q13 = __half2float(qh[(size_t)(ed.y >> 16) * D_FEAT + lane]);
        float q14 = __half2float(qh[(size_t)(ed.z >> 16) * D_FEAT + lane]);
        float q15 = __half2float(qh[(size_t)(ed.w >> 16) * D_FEAT + lane]);
        acc = fmaf(q0,  entry_w(ea.x), acc);
        acc = fmaf(q1,  entry_w(ea.y), acc);
        acc = fmaf(q2,  entry_w(ea.z), acc);
        acc = fmaf(q3,  entry_w(ea.w), acc);
        acc = fmaf(q4,  entry_w(eb.x), acc);
        acc = fmaf(q5,  entry_w(eb.y), acc);
        acc = fmaf(q6,  entry_w(eb.z), acc);
        acc = fmaf(q7,  entry_w(eb.w), acc);
        acc = fmaf(q8,  entry_w(ec.x), acc);
        acc = fmaf(q9,  entry_w(ec.y), acc);
        acc = fmaf(q10, entry_w(ec.z), acc);
        acc = fmaf(q11, entry_w(ec.w), acc);
        acc = fmaf(q12, entry_w(ed.x), acc);
        acc = fmaf(q13, entry_w(ed.y), acc);
        acc = fmaf(q14, entry_w(ed.z), acc);
        acc = fmaf(q15, entry_w(ed.w), acc);
    }
    for (; i < c; i += 4) {                     // masked tail group
        uint4 ea = *reinterpret_cast<const uint4*>(p + i);
        unsigned e0 = (i + 0 < c) ? ea.x : 0u;  // masked: src=0, w=fp16(0)
        unsigned e1 = (i + 1 < c) ? ea.y : 0u;
        unsigned e2 = (i + 2 < c) ? ea.z : 0u;
        unsigned e3 = (i + 3 < c) ? ea.w : 0u;
        float q0 = __half2float(qh[(size_t)(e0 >> 16) * D_FEAT + lane]);
        float q1 = __half2float(qh[(size_t)(e1 >> 16) * D_FEAT + lane]);
        float q2 = __half2float(qh[(size_t)(e2 >> 16) * D_FEAT + lane]);
        float q3 = __half2float(qh[(size_t)(e3 >> 16) * D_FEAT + lane]);
        acc = fmaf(q0, entry_w(e0), acc);
        acc = fmaf(q1, entry_w(e1), acc);
        acc = fmaf(q2, entry_w(e2), acc);
        acc = fmaf(q3, entry_w(e3), acc);
    }

    // Spill edges (normally zero; fp32 path, wave-uniform loads).
    const int nsp = min(*spillcnt, SPILL_CAP);
    for (int k = 0; k < nsp; ++k) {
        uint2 u = spill[k];
        if ((u.x >> 16) == (unsigned)node)
            acc = fmaf(queue[(size_t)(u.x & 0xffffu) * D_FEAT + lane],
                       __uint_as_float(u.y), acc);
    }

    out[(size_t)node * D_FEAT + lane] = acc;
}

// --- Fallback (round-1 scatter) if ws_size is ever too small ---------------
__global__ void __launch_bounds__(256)
scatter_add_kernel(const float* __restrict__ queue,
                   const float* __restrict__ weight,
                   const int* __restrict__ src,
                   const int* __restrict__ dst,
                   float* __restrict__ out) {
    long long tid = (long long)blockIdx.x * blockDim.x + threadIdx.x;
    int e = (int)(tid >> 4);
    int c = ((int)tid & 15) << 2;
    if (e >= N_EDGES) return;
    int s = src[e], d = dst[e];
    float w = weight[e];
    const float4 q = *reinterpret_cast<const float4*>(queue + (size_t)s * D_FEAT + c);
    float* o = out + (size_t)d * D_FEAT + c;
    atomicAdd(o + 0, q.x * w);
    atomicAdd(o + 1, q.y * w);
    atomicAdd(o + 2, q.z * w);
    atomicAdd(o + 3, q.w * w);
}

extern "C" void kernel_launch(void* const* d_in, const int* in_sizes, int n_in,
                              void* d_out, int out_size, void* d_ws, size_t ws_size,
                              hipStream_t stream) {
    const float* queue  = (const float*)d_in[0];
    const float* weight = (const float*)d_in[1];
    const int*   src    = (const int*)d_in[2];
    const int*   dst    = (const int*)d_in[3];
    float* out = (float*)d_out;

    // Workspace layout (16B-aligned blocks):
    //   csr:      N_NODES*CAP unsigned          (6.4 MB)
    //   qh:       N_NODES*D_FEAT __half         (6.4 MB)
    //   stagebuf: 8*STAGE_BLOCKS*BIN_CAP uint2  (12.6 MB)
    //   spill:    SPILL_CAP uint2               (2 MB)
    //   bincnt:   STAGE_BLOCKS*8 int            (32 KB, fully overwritten)
    //   cnt:      N_NODES int   \ zeroed together
    //   spillcnt: 1 int         /
    const size_t csr_bytes   = (size_t)N_NODES * CAP * sizeof(unsigned);
    const size_t qh_bytes    = (size_t)N_NODES * D_FEAT * sizeof(__half);
    const size_t stage_bytes = (size_t)8 * STAGE_BLOCKS * BIN_CAP * sizeof(uint2);
    const size_t spill_bytes = (size_t)SPILL_CAP * sizeof(uint2);
    const size_t bincnt_bytes = (size_t)STAGE_BLOCKS * 8 * sizeof(int);
    const size_t need = csr_bytes + qh_bytes + stage_bytes + spill_bytes
                      + bincnt_bytes + (size_t)(N_NODES + 1) * sizeof(int);

    if (ws_size < need) {  // safety fallback: round-1 scatter path
        hipMemsetAsync(out, 0, (size_t)out_size * sizeof(float), stream);
        const long long total = (long long)N_EDGES * 16;
        scatter_add_kernel<<<(int)((total + 255) / 256), 256, 0, stream>>>(
            queue, weight, src, dst, out);
        return;
    }

    char* ws = (char*)d_ws;
    unsigned* csr   = (unsigned*)ws;
    __half* qh      = (__half*)(ws + csr_bytes);
    uint2* stagebuf = (uint2*)(ws + csr_bytes + qh_bytes);
    uint2* spill    = (uint2*)(ws + csr_bytes + qh_bytes + stage_bytes);
    int* bincnt     = (int*)(ws + csr_bytes + qh_bytes + stage_bytes + spill_bytes);
    int* cnt        = bincnt + STAGE_BLOCKS * 8;
    int* spillcnt   = cnt + N_NODES;

    hipMemsetAsync(cnt, 0, (size_t)(N_NODES + 1) * sizeof(int), stream);

    stage_kernel<<<STAGE_BLOCKS, 256, 0, stream>>>(
        src, dst, weight, queue, qh, stagebuf, bincnt, spill, spillcnt);
    build_kernel<<<BUILD_BLOCKS, 256, 0, stream>>>(
        stagebuf, bincnt, cnt, csr, spill, spillcnt);
    pull_kernel<<<(N_NODES + 3) / 4, 256, 0, stream>>>(
        qh, queue, csr, cnt, spill, spillcnt, out);
}